// Round 1
// baseline (1556.645 us; speedup 1.0000x reference)
//
#include <hip/hip_runtime.h>

#define D 64
#define BN_EPS 1e-5f

// ---------------------------------------------------------------------------
// Scatter-sum aggregation: agg[dst] += x[src] for every edge.
// 16 threads per edge, each handles 4 contiguous features (float4 read,
// 4 scalar fp32 global atomics). Baseline; atomic storm expected to dominate.
// ---------------------------------------------------------------------------
__global__ __launch_bounds__(256) void agg_kernel(
    const float* __restrict__ x, const int* __restrict__ srcs,
    const int* __restrict__ dsts, float* __restrict__ agg, long long nwork)
{
    long long gid = (long long)blockIdx.x * 256 + threadIdx.x;
    if (gid >= nwork) return;
    long long e = gid >> 4;
    int q = ((int)gid & 15) << 2;
    long long s = srcs[e];
    long long d = dsts[e];
    float4 v = *(const float4*)(x + s * D + q);
    float* a = agg + d * D + q;
    atomicAdd(a + 0, v.x);
    atomicAdd(a + 1, v.y);
    atomicAdd(a + 2, v.z);
    atomicAdd(a + 3, v.w);
}

// ---------------------------------------------------------------------------
// Fused (input-transform -> 64x64 matmul -> bias) + batch-stat accumulation.
// MODE 0: z = (1+eps)*x + agg            (GIN combine, first Linear)
// MODE 1: z = relu(h*scale + shift)      (BN1+ReLU, second Linear)
// Each lane owns one output column: W column in 64 VGPRs; the z row is
// broadcast through a per-wave LDS buffer read as float4 (ds_read_b128,
// wave-synchronous, no __syncthreads in the loop).
// ---------------------------------------------------------------------------
template<int MODE>
__global__ __launch_bounds__(256) void mlp_kernel(
    const float* __restrict__ xin, const float* __restrict__ in2,
    const float* __restrict__ W, const float* __restrict__ bias,
    const float* __restrict__ eps_p, const float* __restrict__ coef,
    float* __restrict__ out_h, float* __restrict__ stats, int N)
{
    __shared__ __align__(16) float zbuf[4][64];
    __shared__ float red[2][4][64];
    const int lane = threadIdx.x & 63;
    const int wid = threadIdx.x >> 6;

    float w[64];
    #pragma unroll
    for (int k = 0; k < 64; ++k) w[k] = W[k * 64 + lane];
    const float b = bias[lane];

    float epsv = 0.f, sc = 0.f, sh = 0.f;
    if (MODE == 0) {
        epsv = 1.0f + eps_p[0];
    } else {
        sc = coef[lane];
        sh = coef[64 + lane];
    }

    float s = 0.f, ss = 0.f;
    const int step = gridDim.x * 4;
    for (int r = blockIdx.x * 4 + wid; r < N; r += step) {
        long long base = (long long)r * D + lane;
        float z;
        if (MODE == 0) {
            z = fmaf(epsv, xin[base], in2[base]);
        } else {
            z = fmaxf(fmaf(in2[base], sc, sh), 0.f);
        }
        zbuf[wid][lane] = z;   // wave-local; compiler inserts lgkmcnt wait
        float acc = b;
        #pragma unroll
        for (int k = 0; k < 64; k += 4) {
            float4 zv = *(const float4*)&zbuf[wid][k];   // broadcast b128
            acc = fmaf(zv.x, w[k + 0], acc);
            acc = fmaf(zv.y, w[k + 1], acc);
            acc = fmaf(zv.z, w[k + 2], acc);
            acc = fmaf(zv.w, w[k + 3], acc);
        }
        out_h[base] = acc;
        s += acc;
        ss = fmaf(acc, acc, ss);
    }

    red[0][wid][lane] = s;
    red[1][wid][lane] = ss;
    __syncthreads();
    if (wid == 0) {
        float S  = red[0][0][lane] + red[0][1][lane] + red[0][2][lane] + red[0][3][lane];
        float SS = red[1][0][lane] + red[1][1][lane] + red[1][2][lane] + red[1][3][lane];
        atomicAdd(&stats[lane], S);
        atomicAdd(&stats[64 + lane], SS);
    }
}

// stats -> per-column (scale, shift) for BN: y = h*scale + shift
__global__ void finalize_kernel(const float* __restrict__ stats,
                                const float* __restrict__ gamma,
                                const float* __restrict__ beta,
                                float* __restrict__ coef, float invN)
{
    int c = threadIdx.x;
    float mean = stats[c] * invN;
    float var  = fmaf(-mean, mean, stats[64 + c] * invN);  // biased variance
    float istd = rsqrtf(var + BN_EPS);
    float scv  = gamma[c] * istd;
    coef[c]      = scv;
    coef[64 + c] = fmaf(-mean, scv, beta[c]);
}

// out = x + relu(bn2(h2)), float4 per thread
__global__ __launch_bounds__(256) void final_kernel(
    const float* __restrict__ x, const float* __restrict__ h2,
    const float* __restrict__ coef, float* __restrict__ out, int tot4)
{
    int gid = blockIdx.x * 256 + threadIdx.x;
    if (gid >= tot4) return;
    int c = (gid & 15) << 2;
    float4 h  = ((const float4*)h2)[gid];
    float4 xv = ((const float4*)x)[gid];
    float4 o;
    o.x = xv.x + fmaxf(fmaf(h.x, coef[c + 0], coef[64 + c + 0]), 0.f);
    o.y = xv.y + fmaxf(fmaf(h.y, coef[c + 1], coef[64 + c + 1]), 0.f);
    o.z = xv.z + fmaxf(fmaf(h.z, coef[c + 2], coef[64 + c + 2]), 0.f);
    o.w = xv.w + fmaxf(fmaf(h.w, coef[c + 3], coef[64 + c + 3]), 0.f);
    ((float4*)out)[gid] = o;
}

extern "C" void kernel_launch(void* const* d_in, const int* in_sizes, int n_in,
                              void* d_out, int out_size, void* d_ws, size_t ws_size,
                              hipStream_t stream)
{
    const float* x     = (const float*)d_in[0];
    const int*   ei    = (const int*)d_in[1];   // (2,E) int32 (JAX default int)
    const float* eps   = (const float*)d_in[2];
    const float* W1    = (const float*)d_in[3];
    const float* b1    = (const float*)d_in[4];
    const float* g1    = (const float*)d_in[5];
    const float* beta1 = (const float*)d_in[6];
    const float* W2    = (const float*)d_in[7];
    const float* b2    = (const float*)d_in[8];
    const float* gh    = (const float*)d_in[9];
    const float* betah = (const float*)d_in[10];

    const int       N = in_sizes[0] / D;
    const long long E = in_sizes[1] / 2;
    float* out = (float*)d_out;

    // ws layout: [agg/h2 : N*D] [stats : 256] [coef : 256]
    float* agg   = (float*)d_ws;
    float* stats = agg + (size_t)N * D;
    float* coef  = stats + 256;
    float* h1    = out;   // d_out as scratch for h1; fully overwritten at the end
    float* h2    = agg;   // reuse agg buffer once consumed

    // zero agg + stats in one contiguous memset (ws is poisoned each call)
    hipMemsetAsync(agg, 0, sizeof(float) * ((size_t)N * D + 256), stream);

    long long nwork = E * 16;   // 16 threads per edge
    int gb = (int)((nwork + 255) / 256);
    agg_kernel<<<gb, 256, 0, stream>>>(x, ei, ei + E, agg, nwork);

    mlp_kernel<0><<<1250, 256, 0, stream>>>(x, agg, W1, b1, eps, nullptr,
                                            h1, stats, N);
    finalize_kernel<<<1, 64, 0, stream>>>(stats, g1, beta1, coef, 1.0f / N);

    mlp_kernel<1><<<1250, 256, 0, stream>>>(nullptr, h1, W2, b2, nullptr, coef,
                                            h2, stats + 128, N);
    finalize_kernel<<<1, 64, 0, stream>>>(stats + 128, gh, betah, coef + 128,
                                          1.0f / N);

    int tot4 = N * (D / 4);
    final_kernel<<<(tot4 + 255) / 256, 256, 0, stream>>>(x, h2, coef + 128,
                                                         out, tot4);
}

// Round 2
// 575.348 us; speedup vs baseline: 2.7056x; 2.7056x over previous
//
#include <hip/hip_runtime.h>

#define D 64
#define BN_EPS 1e-5f
#define SCAN_ELEMS 1024   // elements per scan1 block (256 thr x 4)

// ---------------------------------------------------------------------------
// CSR build step 1: degree histogram over destinations.
// ---------------------------------------------------------------------------
__global__ __launch_bounds__(256) void hist_kernel(
    const int* __restrict__ dsts, int* __restrict__ deg, int E)
{
    int gid = blockIdx.x * 256 + threadIdx.x;
    if (gid < E) atomicAdd(&deg[dsts[gid]], 1);
}

// ---------------------------------------------------------------------------
// Scan step 1: per-block (1024-elem) exclusive prefix + block sums.
// ---------------------------------------------------------------------------
__global__ __launch_bounds__(256) void scan1_kernel(
    const int* __restrict__ deg, int* __restrict__ pre,
    int* __restrict__ bsum, int N)
{
    __shared__ int lds[256];
    int t = threadIdx.x;
    int base = blockIdx.x * SCAN_ELEMS + t * 4;
    int4 v = make_int4(0, 0, 0, 0);
    if (base + 3 < N) {
        v = *(const int4*)(deg + base);
    } else {
        if (base + 0 < N) v.x = deg[base + 0];
        if (base + 1 < N) v.y = deg[base + 1];
        if (base + 2 < N) v.z = deg[base + 2];
        if (base + 3 < N) v.w = deg[base + 3];
    }
    int s = v.x + v.y + v.z + v.w;
    lds[t] = s;
    __syncthreads();
    for (int off = 1; off < 256; off <<= 1) {
        int add = (t >= off) ? lds[t - off] : 0;
        __syncthreads();
        lds[t] += add;
        __syncthreads();
    }
    int ex = lds[t] - s;   // exclusive prefix of this thread's 4-chunk
    if (base + 0 < N) pre[base + 0] = ex;
    if (base + 1 < N) pre[base + 1] = ex + v.x;
    if (base + 2 < N) pre[base + 2] = ex + v.x + v.y;
    if (base + 3 < N) pre[base + 3] = ex + v.x + v.y + v.z;
    if (t == 255) bsum[blockIdx.x] = lds[255];
}

// ---------------------------------------------------------------------------
// Scan step 2: single block scans block sums (supports up to 256 blocks).
// ---------------------------------------------------------------------------
__global__ __launch_bounds__(256) void scan2_kernel(
    const int* __restrict__ bsum, int* __restrict__ boff, int nb)
{
    __shared__ int lds[256];
    int t = threadIdx.x;
    int v = (t < nb) ? bsum[t] : 0;
    lds[t] = v;
    __syncthreads();
    for (int off = 1; off < 256; off <<= 1) {
        int add = (t >= off) ? lds[t - off] : 0;
        __syncthreads();
        lds[t] += add;
        __syncthreads();
    }
    if (t < nb) boff[t] = lds[t] - v;   // exclusive block offset
}

// ---------------------------------------------------------------------------
// Scan step 3: rowptr[i] = pre[i] + boff[block(i)]; duplicate into cursor.
// ---------------------------------------------------------------------------
__global__ __launch_bounds__(256) void scan3_kernel(
    const int* __restrict__ pre, const int* __restrict__ boff,
    int* __restrict__ rowptr, int* __restrict__ cursor, int N)
{
    int gid = blockIdx.x * 256 + threadIdx.x;
    if (gid < N) {
        int v = pre[gid] + boff[gid / SCAN_ELEMS];
        rowptr[gid] = v;
        cursor[gid] = v;
    }
}

// ---------------------------------------------------------------------------
// CSR fill: csr_src[slot(dst)] = src.
// ---------------------------------------------------------------------------
__global__ __launch_bounds__(256) void fill_kernel(
    const int* __restrict__ srcs, const int* __restrict__ dsts,
    int* __restrict__ cursor, int* __restrict__ csr, int E)
{
    int gid = blockIdx.x * 256 + threadIdx.x;
    if (gid < E) {
        int pos = atomicAdd(&cursor[dsts[gid]], 1);
        csr[pos] = srcs[gid];
    }
}

// ---------------------------------------------------------------------------
// Fused: CSR gather (agg) -> z=(1+eps)x+agg -> z@W1+b1 -> h1, batch stats.
// One wave per row; lane = output column; W1 column held in 64 VGPRs;
// z broadcast through per-wave LDS, read back as float4 (ds_read_b128).
// ---------------------------------------------------------------------------
__global__ __launch_bounds__(256) void gather_mlp1_kernel(
    const float* __restrict__ x, const int* __restrict__ rowptr,
    const int* __restrict__ deg, const int* __restrict__ csr,
    const float* __restrict__ W, const float* __restrict__ bias,
    const float* __restrict__ eps_p,
    float* __restrict__ out_h, float* __restrict__ stats, int N)
{
    __shared__ __align__(16) float zbuf[4][64];
    __shared__ float red[2][4][64];
    const int lane = threadIdx.x & 63;
    const int wid = threadIdx.x >> 6;

    float w[64];
    #pragma unroll
    for (int k = 0; k < 64; ++k) w[k] = W[k * 64 + lane];
    const float b = bias[lane];
    const float epsv = 1.0f + eps_p[0];

    float s = 0.f, ss = 0.f;
    const int step = gridDim.x * 4;
    for (int r = blockIdx.x * 4 + wid; r < N; r += step) {
        int e0 = rowptr[r];
        int e1 = e0 + deg[r];
        float acc = 0.f;
        for (int e = e0; e < e1; ++e) {
            int sidx = csr[e];                       // wave-uniform broadcast
            acc += x[(long long)sidx * D + lane];    // coalesced 256B row
        }
        long long base = (long long)r * D + lane;
        float z = fmaf(epsv, x[base], acc);

        zbuf[wid][lane] = z;   // wave-local; compiler inserts lgkmcnt wait
        float zacc = b;
        #pragma unroll
        for (int k = 0; k < 64; k += 4) {
            float4 zv = *(const float4*)&zbuf[wid][k];
            zacc = fmaf(zv.x, w[k + 0], zacc);
            zacc = fmaf(zv.y, w[k + 1], zacc);
            zacc = fmaf(zv.z, w[k + 2], zacc);
            zacc = fmaf(zv.w, w[k + 3], zacc);
        }
        out_h[base] = zacc;
        s += zacc;
        ss = fmaf(zacc, zacc, ss);
    }

    red[0][wid][lane] = s;
    red[1][wid][lane] = ss;
    __syncthreads();
    if (wid == 0) {
        float S  = red[0][0][lane] + red[0][1][lane] + red[0][2][lane] + red[0][3][lane];
        float SS = red[1][0][lane] + red[1][1][lane] + red[1][2][lane] + red[1][3][lane];
        atomicAdd(&stats[lane], S);
        atomicAdd(&stats[64 + lane], SS);
    }
}

// ---------------------------------------------------------------------------
// Second linear: z = relu(h1*scale+shift) -> z@W2+b2 -> h2, batch stats.
// ---------------------------------------------------------------------------
__global__ __launch_bounds__(256) void mlp2_kernel(
    const float* __restrict__ in2, const float* __restrict__ W,
    const float* __restrict__ bias, const float* __restrict__ coef,
    float* __restrict__ out_h, float* __restrict__ stats, int N)
{
    __shared__ __align__(16) float zbuf[4][64];
    __shared__ float red[2][4][64];
    const int lane = threadIdx.x & 63;
    const int wid = threadIdx.x >> 6;

    float w[64];
    #pragma unroll
    for (int k = 0; k < 64; ++k) w[k] = W[k * 64 + lane];
    const float b = bias[lane];
    const float sc = coef[lane];
    const float sh = coef[64 + lane];

    float s = 0.f, ss = 0.f;
    const int step = gridDim.x * 4;
    for (int r = blockIdx.x * 4 + wid; r < N; r += step) {
        long long base = (long long)r * D + lane;
        float z = fmaxf(fmaf(in2[base], sc, sh), 0.f);
        zbuf[wid][lane] = z;
        float acc = b;
        #pragma unroll
        for (int k = 0; k < 64; k += 4) {
            float4 zv = *(const float4*)&zbuf[wid][k];
            acc = fmaf(zv.x, w[k + 0], acc);
            acc = fmaf(zv.y, w[k + 1], acc);
            acc = fmaf(zv.z, w[k + 2], acc);
            acc = fmaf(zv.w, w[k + 3], acc);
        }
        out_h[base] = acc;
        s += acc;
        ss = fmaf(acc, acc, ss);
    }

    red[0][wid][lane] = s;
    red[1][wid][lane] = ss;
    __syncthreads();
    if (wid == 0) {
        float S  = red[0][0][lane] + red[0][1][lane] + red[0][2][lane] + red[0][3][lane];
        float SS = red[1][0][lane] + red[1][1][lane] + red[1][2][lane] + red[1][3][lane];
        atomicAdd(&stats[lane], S);
        atomicAdd(&stats[64 + lane], SS);
    }
}

// stats -> per-column (scale, shift) for BN: y = h*scale + shift
__global__ void finalize_kernel(const float* __restrict__ stats,
                                const float* __restrict__ gamma,
                                const float* __restrict__ beta,
                                float* __restrict__ coef, float invN)
{
    int c = threadIdx.x;
    float mean = stats[c] * invN;
    float var  = fmaf(-mean, mean, stats[64 + c] * invN);  // biased variance
    float istd = rsqrtf(var + BN_EPS);
    float scv  = gamma[c] * istd;
    coef[c]      = scv;
    coef[64 + c] = fmaf(-mean, scv, beta[c]);
}

// out = x + relu(bn2(h2)), float4 per thread
__global__ __launch_bounds__(256) void final_kernel(
    const float* __restrict__ x, const float* __restrict__ h2,
    const float* __restrict__ coef, float* __restrict__ out, int tot4)
{
    int gid = blockIdx.x * 256 + threadIdx.x;
    if (gid >= tot4) return;
    int c = (gid & 15) << 2;
    float4 h  = ((const float4*)h2)[gid];
    float4 xv = ((const float4*)x)[gid];
    float4 o;
    o.x = xv.x + fmaxf(fmaf(h.x, coef[c + 0], coef[64 + c + 0]), 0.f);
    o.y = xv.y + fmaxf(fmaf(h.y, coef[c + 1], coef[64 + c + 1]), 0.f);
    o.z = xv.z + fmaxf(fmaf(h.z, coef[c + 2], coef[64 + c + 2]), 0.f);
    o.w = xv.w + fmaxf(fmaf(h.w, coef[c + 3], coef[64 + c + 3]), 0.f);
    ((float4*)out)[gid] = o;
}

extern "C" void kernel_launch(void* const* d_in, const int* in_sizes, int n_in,
                              void* d_out, int out_size, void* d_ws, size_t ws_size,
                              hipStream_t stream)
{
    const float* x     = (const float*)d_in[0];
    const int*   ei    = (const int*)d_in[1];   // (2,E) int32
    const float* eps   = (const float*)d_in[2];
    const float* W1    = (const float*)d_in[3];
    const float* b1    = (const float*)d_in[4];
    const float* g1    = (const float*)d_in[5];
    const float* beta1 = (const float*)d_in[6];
    const float* W2    = (const float*)d_in[7];
    const float* b2    = (const float*)d_in[8];
    const float* gh    = (const float*)d_in[9];
    const float* betah = (const float*)d_in[10];

    const int N = in_sizes[0] / D;
    const int E = in_sizes[1] / 2;
    const int* srcs = ei;
    const int* dsts = ei + E;
    float* out = (float*)d_out;

    // ws layout (all 16B-aligned for N=100000):
    int*   deg    = (int*)d_ws;            // N
    int*   rowptr = deg + N;               // N
    int*   cursor = rowptr + N;            // N
    int*   pre    = cursor + N;            // N
    int*   bsum   = pre + N;               // 256
    int*   boff   = bsum + 256;            // 256
    float* stats  = (float*)(boff + 256);  // 256 (two sets of 128)
    float* coef   = stats + 256;           // 256 (two sets of 128)
    int*   csr    = (int*)(coef + 256);    // E
    float* h2     = (float*)(csr + E);     // N*D
    float* h1     = out;                   // d_out as scratch; overwritten at end

    hipMemsetAsync(deg, 0, sizeof(int) * N, stream);
    hipMemsetAsync(stats, 0, sizeof(float) * 256, stream);

    int ebl = (E + 255) / 256;
    hist_kernel<<<ebl, 256, 0, stream>>>(dsts, deg, E);

    int nb = (N + SCAN_ELEMS - 1) / SCAN_ELEMS;   // 98 <= 256
    scan1_kernel<<<nb, 256, 0, stream>>>(deg, pre, bsum, N);
    scan2_kernel<<<1, 256, 0, stream>>>(bsum, boff, nb);
    scan3_kernel<<<(N + 255) / 256, 256, 0, stream>>>(pre, boff, rowptr, cursor, N);

    fill_kernel<<<ebl, 256, 0, stream>>>(srcs, dsts, cursor, csr, E);

    gather_mlp1_kernel<<<1250, 256, 0, stream>>>(x, rowptr, deg, csr, W1, b1,
                                                 eps, h1, stats, N);
    finalize_kernel<<<1, 64, 0, stream>>>(stats, g1, beta1, coef, 1.0f / N);

    mlp2_kernel<<<1250, 256, 0, stream>>>(h1, W2, b2, coef, h2, stats + 128, N);
    finalize_kernel<<<1, 64, 0, stream>>>(stats + 128, gh, betah, coef + 128,
                                          1.0f / N);

    int tot4 = N * (D / 4);
    final_kernel<<<(tot4 + 255) / 256, 256, 0, stream>>>(x, h2, coef + 128,
                                                         out, tot4);
}

// Round 3
// 541.285 us; speedup vs baseline: 2.8758x; 1.0629x over previous
//
#include <hip/hip_runtime.h>

#define D 64
#define BN_EPS 1e-5f
#define SCAN_ELEMS 1024   // elements per scan1 block (256 thr x 4)

// ---------------------------------------------------------------------------
// CSR build step 1: degree histogram over destinations.
// ---------------------------------------------------------------------------
__global__ __launch_bounds__(256) void hist_kernel(
    const int* __restrict__ dsts, int* __restrict__ deg, int E)
{
    int gid = blockIdx.x * 256 + threadIdx.x;
    if (gid < E) atomicAdd(&deg[dsts[gid]], 1);
}

// ---------------------------------------------------------------------------
// Scan step 1: per-block (1024-elem) exclusive prefix + block sums.
// ---------------------------------------------------------------------------
__global__ __launch_bounds__(256) void scan1_kernel(
    const int* __restrict__ deg, int* __restrict__ pre,
    int* __restrict__ bsum, int N)
{
    __shared__ int lds[256];
    int t = threadIdx.x;
    int base = blockIdx.x * SCAN_ELEMS + t * 4;
    int4 v = make_int4(0, 0, 0, 0);
    if (base + 3 < N) {
        v = *(const int4*)(deg + base);
    } else {
        if (base + 0 < N) v.x = deg[base + 0];
        if (base + 1 < N) v.y = deg[base + 1];
        if (base + 2 < N) v.z = deg[base + 2];
        if (base + 3 < N) v.w = deg[base + 3];
    }
    int s = v.x + v.y + v.z + v.w;
    lds[t] = s;
    __syncthreads();
    for (int off = 1; off < 256; off <<= 1) {
        int add = (t >= off) ? lds[t - off] : 0;
        __syncthreads();
        lds[t] += add;
        __syncthreads();
    }
    int ex = lds[t] - s;   // exclusive prefix of this thread's 4-chunk
    if (base + 0 < N) pre[base + 0] = ex;
    if (base + 1 < N) pre[base + 1] = ex + v.x;
    if (base + 2 < N) pre[base + 2] = ex + v.x + v.y;
    if (base + 3 < N) pre[base + 3] = ex + v.x + v.y + v.z;
    if (t == 255) bsum[blockIdx.x] = lds[255];
}

// ---------------------------------------------------------------------------
// Scan step 2: single block scans block sums (supports up to 256 blocks).
// ---------------------------------------------------------------------------
__global__ __launch_bounds__(256) void scan2_kernel(
    const int* __restrict__ bsum, int* __restrict__ boff, int nb)
{
    __shared__ int lds[256];
    int t = threadIdx.x;
    int v = (t < nb) ? bsum[t] : 0;
    lds[t] = v;
    __syncthreads();
    for (int off = 1; off < 256; off <<= 1) {
        int add = (t >= off) ? lds[t - off] : 0;
        __syncthreads();
        lds[t] += add;
        __syncthreads();
    }
    if (t < nb) boff[t] = lds[t] - v;   // exclusive block offset
}

// ---------------------------------------------------------------------------
// Scan step 3: rowptr[i] = pre[i] + boff[block(i)]; duplicate into cursor.
// ---------------------------------------------------------------------------
__global__ __launch_bounds__(256) void scan3_kernel(
    const int* __restrict__ pre, const int* __restrict__ boff,
    int* __restrict__ rowptr, int* __restrict__ cursor, int N)
{
    int gid = blockIdx.x * 256 + threadIdx.x;
    if (gid < N) {
        int v = pre[gid] + boff[gid / SCAN_ELEMS];
        rowptr[gid] = v;
        cursor[gid] = v;
    }
}

// ---------------------------------------------------------------------------
// CSR fill: csr_src[slot(dst)] = src. Non-temporal scattered store.
// ---------------------------------------------------------------------------
__global__ __launch_bounds__(256) void fill_kernel(
    const int* __restrict__ srcs, const int* __restrict__ dsts,
    int* __restrict__ cursor, int* __restrict__ csr, int E)
{
    int gid = blockIdx.x * 256 + threadIdx.x;
    if (gid < E) {
        int pos = atomicAdd(&cursor[dsts[gid]], 1);
        __builtin_nontemporal_store(srcs[gid], &csr[pos]);
    }
}

// ---------------------------------------------------------------------------
// Fused: CSR gather (agg) -> z=(1+eps)x+agg -> z@W1+b1 -> h1, batch stats.
// One wave per row; lane = output column. Gather unrolled x4 with
// independent accumulators: 4 row-loads in flight per wave (MLP), breaking
// the serial load->add->load dependence that made R2 latency-bound.
// ---------------------------------------------------------------------------
__global__ __launch_bounds__(256) void gather_mlp1_kernel(
    const float* __restrict__ x, const int* __restrict__ rowptr,
    const int* __restrict__ deg, const int* __restrict__ csr,
    const float* __restrict__ W, const float* __restrict__ bias,
    const float* __restrict__ eps_p,
    float* __restrict__ out_h, float* __restrict__ stats, int N)
{
    __shared__ __align__(16) float zbuf[4][64];
    __shared__ float red[2][4][64];
    const int lane = threadIdx.x & 63;
    const int wid = threadIdx.x >> 6;

    float w[64];
    #pragma unroll
    for (int k = 0; k < 64; ++k) w[k] = W[k * 64 + lane];
    const float b = bias[lane];
    const float epsv = 1.0f + eps_p[0];

    float s = 0.f, ss = 0.f;
    const int step = gridDim.x * 4;
    for (int r = blockIdx.x * 4 + wid; r < N; r += step) {
        int e0 = rowptr[r];
        int e1 = e0 + deg[r];
        float a0 = 0.f, a1 = 0.f, a2 = 0.f, a3 = 0.f;
        int e = e0;
        for (; e + 3 < e1; e += 4) {
            int s0 = csr[e + 0];
            int s1 = csr[e + 1];
            int s2 = csr[e + 2];
            int s3 = csr[e + 3];
            float v0 = x[(long long)s0 * D + lane];
            float v1 = x[(long long)s1 * D + lane];
            float v2 = x[(long long)s2 * D + lane];
            float v3 = x[(long long)s3 * D + lane];
            a0 += v0; a1 += v1; a2 += v2; a3 += v3;
        }
        for (; e < e1; ++e) a0 += x[(long long)csr[e] * D + lane];
        long long base = (long long)r * D + lane;
        float z = fmaf(epsv, x[base], (a0 + a1) + (a2 + a3));

        zbuf[wid][lane] = z;   // wave-local; compiler inserts lgkmcnt wait
        float zacc = b;
        #pragma unroll
        for (int k = 0; k < 64; k += 4) {
            float4 zv = *(const float4*)&zbuf[wid][k];
            zacc = fmaf(zv.x, w[k + 0], zacc);
            zacc = fmaf(zv.y, w[k + 1], zacc);
            zacc = fmaf(zv.z, w[k + 2], zacc);
            zacc = fmaf(zv.w, w[k + 3], zacc);
        }
        out_h[base] = zacc;
        s += zacc;
        ss = fmaf(zacc, zacc, ss);
    }

    red[0][wid][lane] = s;
    red[1][wid][lane] = ss;
    __syncthreads();
    if (wid == 0) {
        float S  = red[0][0][lane] + red[0][1][lane] + red[0][2][lane] + red[0][3][lane];
        float SS = red[1][0][lane] + red[1][1][lane] + red[1][2][lane] + red[1][3][lane];
        atomicAdd(&stats[lane], S);
        atomicAdd(&stats[64 + lane], SS);
    }
}

// ---------------------------------------------------------------------------
// Second linear: z = relu(h1*scale+shift) -> z@W2+b2 -> h2, batch stats.
// ---------------------------------------------------------------------------
__global__ __launch_bounds__(256) void mlp2_kernel(
    const float* __restrict__ in2, const float* __restrict__ W,
    const float* __restrict__ bias, const float* __restrict__ coef,
    float* __restrict__ out_h, float* __restrict__ stats, int N)
{
    __shared__ __align__(16) float zbuf[4][64];
    __shared__ float red[2][4][64];
    const int lane = threadIdx.x & 63;
    const int wid = threadIdx.x >> 6;

    float w[64];
    #pragma unroll
    for (int k = 0; k < 64; ++k) w[k] = W[k * 64 + lane];
    const float b = bias[lane];
    const float sc = coef[lane];
    const float sh = coef[64 + lane];

    float s = 0.f, ss = 0.f;
    const int step = gridDim.x * 4;
    for (int r = blockIdx.x * 4 + wid; r < N; r += step) {
        long long base = (long long)r * D + lane;
        float z = fmaxf(fmaf(in2[base], sc, sh), 0.f);
        zbuf[wid][lane] = z;
        float acc = b;
        #pragma unroll
        for (int k = 0; k < 64; k += 4) {
            float4 zv = *(const float4*)&zbuf[wid][k];
            acc = fmaf(zv.x, w[k + 0], acc);
            acc = fmaf(zv.y, w[k + 1], acc);
            acc = fmaf(zv.z, w[k + 2], acc);
            acc = fmaf(zv.w, w[k + 3], acc);
        }
        out_h[base] = acc;
        s += acc;
        ss = fmaf(acc, acc, ss);
    }

    red[0][wid][lane] = s;
    red[1][wid][lane] = ss;
    __syncthreads();
    if (wid == 0) {
        float S  = red[0][0][lane] + red[0][1][lane] + red[0][2][lane] + red[0][3][lane];
        float SS = red[1][0][lane] + red[1][1][lane] + red[1][2][lane] + red[1][3][lane];
        atomicAdd(&stats[lane], S);
        atomicAdd(&stats[64 + lane], SS);
    }
}

// stats -> per-column (scale, shift) for BN: y = h*scale + shift
__global__ void finalize_kernel(const float* __restrict__ stats,
                                const float* __restrict__ gamma,
                                const float* __restrict__ beta,
                                float* __restrict__ coef, float invN)
{
    int c = threadIdx.x;
    float mean = stats[c] * invN;
    float var  = fmaf(-mean, mean, stats[64 + c] * invN);  // biased variance
    float istd = rsqrtf(var + BN_EPS);
    float scv  = gamma[c] * istd;
    coef[c]      = scv;
    coef[64 + c] = fmaf(-mean, scv, beta[c]);
}

// out = x + relu(bn2(h2)), float4 per thread
__global__ __launch_bounds__(256) void final_kernel(
    const float* __restrict__ x, const float* __restrict__ h2,
    const float* __restrict__ coef, float* __restrict__ out, int tot4)
{
    int gid = blockIdx.x * 256 + threadIdx.x;
    if (gid >= tot4) return;
    int c = (gid & 15) << 2;
    float4 h  = ((const float4*)h2)[gid];
    float4 xv = ((const float4*)x)[gid];
    float4 o;
    o.x = xv.x + fmaxf(fmaf(h.x, coef[c + 0], coef[64 + c + 0]), 0.f);
    o.y = xv.y + fmaxf(fmaf(h.y, coef[c + 1], coef[64 + c + 1]), 0.f);
    o.z = xv.z + fmaxf(fmaf(h.z, coef[c + 2], coef[64 + c + 2]), 0.f);
    o.w = xv.w + fmaxf(fmaf(h.w, coef[c + 3], coef[64 + c + 3]), 0.f);
    ((float4*)out)[gid] = o;
}

extern "C" void kernel_launch(void* const* d_in, const int* in_sizes, int n_in,
                              void* d_out, int out_size, void* d_ws, size_t ws_size,
                              hipStream_t stream)
{
    const float* x     = (const float*)d_in[0];
    const int*   ei    = (const int*)d_in[1];   // (2,E) int32
    const float* eps   = (const float*)d_in[2];
    const float* W1    = (const float*)d_in[3];
    const float* b1    = (const float*)d_in[4];
    const float* g1    = (const float*)d_in[5];
    const float* beta1 = (const float*)d_in[6];
    const float* W2    = (const float*)d_in[7];
    const float* b2    = (const float*)d_in[8];
    const float* gh    = (const float*)d_in[9];
    const float* betah = (const float*)d_in[10];

    const int N = in_sizes[0] / D;
    const int E = in_sizes[1] / 2;
    const int* srcs = ei;
    const int* dsts = ei + E;
    float* out = (float*)d_out;

    // ws layout (all 16B-aligned for N=100000):
    int*   deg    = (int*)d_ws;            // N
    int*   rowptr = deg + N;               // N
    int*   cursor = rowptr + N;            // N
    int*   pre    = cursor + N;            // N
    int*   bsum   = pre + N;               // 256
    int*   boff   = bsum + 256;            // 256
    float* stats  = (float*)(boff + 256);  // 256 (two sets of 128)
    float* coef   = stats + 256;           // 256 (two sets of 128)
    int*   csr    = (int*)(coef + 256);    // E
    float* h2     = (float*)(csr + E);     // N*D
    float* h1     = out;                   // d_out as scratch; overwritten at end

    hipMemsetAsync(deg, 0, sizeof(int) * N, stream);
    hipMemsetAsync(stats, 0, sizeof(float) * 256, stream);

    int ebl = (E + 255) / 256;
    hist_kernel<<<ebl, 256, 0, stream>>>(dsts, deg, E);

    int nb = (N + SCAN_ELEMS - 1) / SCAN_ELEMS;   // 98 <= 256
    scan1_kernel<<<nb, 256, 0, stream>>>(deg, pre, bsum, N);
    scan2_kernel<<<1, 256, 0, stream>>>(bsum, boff, nb);
    scan3_kernel<<<(N + 255) / 256, 256, 0, stream>>>(pre, boff, rowptr, cursor, N);

    fill_kernel<<<ebl, 256, 0, stream>>>(srcs, dsts, cursor, csr, E);

    gather_mlp1_kernel<<<2500, 256, 0, stream>>>(x, rowptr, deg, csr, W1, b1,
                                                 eps, h1, stats, N);
    finalize_kernel<<<1, 64, 0, stream>>>(stats, g1, beta1, coef, 1.0f / N);

    mlp2_kernel<<<2500, 256, 0, stream>>>(h1, W2, b2, coef, h2, stats + 128, N);
    finalize_kernel<<<1, 64, 0, stream>>>(stats + 128, gh, betah, coef + 128,
                                          1.0f / N);

    int tot4 = N * (D / 4);
    final_kernel<<<(tot4 + 255) / 256, 256, 0, stream>>>(x, h2, coef + 128,
                                                         out, tot4);
}